// Round 1
// baseline (613.605 us; speedup 1.0000x reference)
//
#include <hip/hip_runtime.h>
#include <hip/hip_bf16.h>

#define NEG_SLOPE 0.2f
#define LN_EPS 1e-5f
#define SM_EPS 1e-16f

// ---------------------------------------------------------------------------
// K1: x = X @ W^T   (X:[N,128] f32, W:[128,128] f32, x:[N,128] f32)
// Block = 256 threads, 32 nodes per block. W^T staged in LDS in two K-halves
// (WsT[kk][j], 32KB), X tile transposed (Xs[k][m], 16KB) -> 48KB LDS.
// Wave w handles nodes w*8..w*8+7, lane owns outputs j=lane and j=lane+64.
// ---------------------------------------------------------------------------
__global__ __launch_bounds__(256) void k_gemm(const float* __restrict__ X,
                                              const float* __restrict__ W,
                                              float* __restrict__ xout, int N) {
    __shared__ float WsT[64 * 128];   // [kk][j]
    __shared__ float Xs[128 * 32];    // [k][m]
    const int t = threadIdx.x;
    const int b0 = blockIdx.x * 32;
    const int lane = t & 63;
    const int w = t >> 6;

    // stage X tile (32 nodes x 128 feats = 1024 float4)
    for (int i = 0; i < 4; ++i) {
        int flat = i * 256 + t;          // float4 index
        int m = flat >> 5;               // node in tile
        int kq = flat & 31;              // float4 along k
        int n = b0 + m;
        if (n >= N) n = N - 1;           // clamp (duplicate load, store guarded)
        float4 v = reinterpret_cast<const float4*>(X)[(size_t)n * 32 + kq];
        Xs[(kq * 4 + 0) * 32 + m] = v.x;
        Xs[(kq * 4 + 1) * 32 + m] = v.y;
        Xs[(kq * 4 + 2) * 32 + m] = v.z;
        Xs[(kq * 4 + 3) * 32 + m] = v.w;
    }

    float acc0[8] = {0.f, 0.f, 0.f, 0.f, 0.f, 0.f, 0.f, 0.f};
    float acc1[8] = {0.f, 0.f, 0.f, 0.f, 0.f, 0.f, 0.f, 0.f};

    for (int kh = 0; kh < 2; ++kh) {
        __syncthreads();   // protect WsT reuse + Xs readiness on first pass
        // stage W^T half: 128 j x 64 k = 2048 float4
        for (int i = 0; i < 8; ++i) {
            int flat = i * 256 + t;
            int j = flat >> 4;           // W row (output index)
            int kq = flat & 15;          // float4 along k within half
            float4 v = reinterpret_cast<const float4*>(W)[j * 32 + kh * 16 + kq];
            WsT[(kq * 4 + 0) * 128 + j] = v.x;
            WsT[(kq * 4 + 1) * 128 + j] = v.y;
            WsT[(kq * 4 + 2) * 128 + j] = v.z;
            WsT[(kq * 4 + 3) * 128 + j] = v.w;
        }
        __syncthreads();

        const int kbase = kh * 64;
#pragma unroll 8
        for (int kk = 0; kk < 64; ++kk) {
            float w0 = WsT[kk * 128 + lane];
            float w1 = WsT[kk * 128 + 64 + lane];
            const float* xrow = &Xs[(kbase + kk) * 32 + w * 8];
            float4 xa = *reinterpret_cast<const float4*>(xrow);
            float4 xb = *reinterpret_cast<const float4*>(xrow + 4);
            acc0[0] += w0 * xa.x;  acc1[0] += w1 * xa.x;
            acc0[1] += w0 * xa.y;  acc1[1] += w1 * xa.y;
            acc0[2] += w0 * xa.z;  acc1[2] += w1 * xa.z;
            acc0[3] += w0 * xa.w;  acc1[3] += w1 * xa.w;
            acc0[4] += w0 * xb.x;  acc1[4] += w1 * xb.x;
            acc0[5] += w0 * xb.y;  acc1[5] += w1 * xb.y;
            acc0[6] += w0 * xb.z;  acc1[6] += w1 * xb.z;
            acc0[7] += w0 * xb.w;  acc1[7] += w1 * xb.w;
        }
    }

#pragma unroll
    for (int i = 0; i < 8; ++i) {
        int n = b0 + w * 8 + i;
        if (n < N) {
            xout[(size_t)n * 128 + lane]      = acc0[i];
            xout[(size_t)n * 128 + 64 + lane] = acc1[i];
        }
    }
}

// ---------------------------------------------------------------------------
// K2: per-node attention logits. One wave per node; lane = feature.
// aAtt[n] = {a_src0, a_src1, a_dst0, a_dst1}
// ---------------------------------------------------------------------------
__global__ __launch_bounds__(256) void k_att(const float* __restrict__ x,
                                             const float* __restrict__ att_src,
                                             const float* __restrict__ att_dst,
                                             float4* __restrict__ aAtt, int N) {
    const int w = threadIdx.x >> 6, lane = threadIdx.x & 63;
    const int n = blockIdx.x * 4 + w;
    if (n >= N) return;
    float x0 = x[(size_t)n * 128 + lane];
    float x1 = x[(size_t)n * 128 + 64 + lane];
    float s0 = x0 * att_src[lane];
    float s1 = x1 * att_src[64 + lane];
    float d0 = x0 * att_dst[lane];
    float d1 = x1 * att_dst[64 + lane];
#pragma unroll
    for (int o = 32; o > 0; o >>= 1) {
        s0 += __shfl_down(s0, o);
        s1 += __shfl_down(s1, o);
        d0 += __shfl_down(d0, o);
        d1 += __shfl_down(d1, o);
    }
    if (lane == 0) aAtt[n] = make_float4(s0, s1, d0, d1);
}

// ---------------------------------------------------------------------------
// CSR build: histogram -> 3-kernel exclusive scan -> scatter
// ---------------------------------------------------------------------------
__global__ void k_hist(const int* __restrict__ ei, int* __restrict__ counts, int E) {
    int i = blockIdx.x * 256 + threadIdx.x;
    if (i < E) atomicAdd(&counts[ei[E + i]], 1);
}

__global__ __launch_bounds__(256) void k_scan1(const int* __restrict__ counts,
                                               int* __restrict__ blockSums, int N) {
    __shared__ int lds[4];
    const int t = threadIdx.x;
    int base = blockIdx.x * 1024 + t * 4;
    int s = 0;
    for (int c = 0; c < 4; ++c) {
        int i = base + c;
        if (i < N) s += counts[i];
    }
    int lane = t & 63, w = t >> 6;
    for (int o = 32; o > 0; o >>= 1) s += __shfl_down(s, o);
    if (lane == 0) lds[w] = s;
    __syncthreads();
    if (t == 0) blockSums[blockIdx.x] = lds[0] + lds[1] + lds[2] + lds[3];
}

__global__ void k_scan2(int* __restrict__ blockSums, int nb) {
    __shared__ int buf[256];
    const int t = threadIdx.x;
    int v = (t < nb) ? blockSums[t] : 0;
    buf[t] = v;
    __syncthreads();
    for (int o = 1; o < 256; o <<= 1) {
        int u = (t >= o) ? buf[t - o] : 0;
        __syncthreads();
        buf[t] += u;
        __syncthreads();
    }
    if (t < nb) blockSums[t] = buf[t] - v;   // exclusive
}

__global__ __launch_bounds__(256) void k_scan3(const int* __restrict__ counts,
                                               const int* __restrict__ blockSums,
                                               int* __restrict__ row_ptr,
                                               int* __restrict__ cursor, int N, int E) {
    __shared__ int lds[4];
    const int t = threadIdx.x;
    int base = blockIdx.x * 1024 + t * 4;
    int c[4];
    int s = 0;
#pragma unroll
    for (int i = 0; i < 4; ++i) {
        int idx = base + i;
        c[i] = (idx < N) ? counts[idx] : 0;
        s += c[i];
    }
    // block exclusive scan of per-thread sums
    int lane = t & 63, w = t >> 6;
    int incl = s;
#pragma unroll
    for (int o = 1; o < 64; o <<= 1) {
        int u = __shfl_up(incl, o);
        if (lane >= o) incl += u;
    }
    if (lane == 63) lds[w] = incl;
    __syncthreads();
    if (t == 0) {
        int run = 0;
        for (int i = 0; i < 4; ++i) { int tmp = lds[i]; lds[i] = run; run += tmp; }
    }
    __syncthreads();
    int off = blockSums[blockIdx.x] + lds[w] + incl - s;
#pragma unroll
    for (int i = 0; i < 4; ++i) {
        int idx = base + i;
        if (idx < N) {
            row_ptr[idx] = off;
            cursor[idx] = off;
            off += c[i];
        }
    }
    if (blockIdx.x == 0 && t == 0) row_ptr[N] = E;
}

__global__ void k_scatter(const int* __restrict__ ei, int* __restrict__ cursor,
                          int* __restrict__ csr_src, int E) {
    int i = blockIdx.x * 256 + threadIdx.x;
    if (i < E) {
        int s = ei[i];
        int d = ei[E + i];
        int pos = atomicAdd(&cursor[d], 1);
        csr_src[pos] = s;
    }
}

// ---------------------------------------------------------------------------
// K5: per-dst-node aggregation + head-mean + bias + LayerNorm.
// One wave per node, lane = feature f (0..63). Single pass: denominator is
// constant per (node, head), so out_h = sum(w_e * x[src]) / sum(w_e).
// Max-subtraction dropped (logits are O(+-3); exp-safe; identical alpha).
// ---------------------------------------------------------------------------
__global__ __launch_bounds__(256) void k_agg(const float* __restrict__ x,
                                             const float2* __restrict__ aAtt,
                                             const int* __restrict__ row_ptr,
                                             const int* __restrict__ csr_src,
                                             const float* __restrict__ bias,
                                             const float* __restrict__ gamma,
                                             const float* __restrict__ beta,
                                             float* __restrict__ out, int N) {
    const int w = threadIdx.x >> 6, lane = threadIdx.x & 63;
    const int n = blockIdx.x * 4 + w;
    if (n >= N) return;

    float2 as = aAtt[(size_t)n * 2];       // {a_src0, a_src1} of this node
    float2 ad = aAtt[(size_t)n * 2 + 1];   // {a_dst0, a_dst1} of this node

    // self loop
    float e0 = as.x + ad.x; e0 = fmaxf(e0, NEG_SLOPE * e0);
    float e1 = as.y + ad.y; e1 = fmaxf(e1, NEG_SLOPE * e1);
    float w0 = __expf(e0), w1 = __expf(e1);
    float D0 = w0, D1 = w1;
    float S0 = w0 * x[(size_t)n * 128 + lane];
    float S1 = w1 * x[(size_t)n * 128 + 64 + lane];

    const int jb = row_ptr[n], je = row_ptr[n + 1];
    for (int j = jb; j < je; ++j) {
        int src = csr_src[j];
        float2 a = aAtt[(size_t)src * 2];
        float f0 = a.x + ad.x; f0 = fmaxf(f0, NEG_SLOPE * f0);
        float f1 = a.y + ad.y; f1 = fmaxf(f1, NEG_SLOPE * f1);
        float u0 = __expf(f0), u1 = __expf(f1);
        D0 += u0; D1 += u1;
        S0 += u0 * x[(size_t)src * 128 + lane];
        S1 += u1 * x[(size_t)src * 128 + 64 + lane];
    }

    float o = 0.5f * (S0 / (D0 + SM_EPS) + S1 / (D1 + SM_EPS)) + bias[lane];

    // LayerNorm over 64 features (one per lane)
    float mu = o;
#pragma unroll
    for (int d = 32; d > 0; d >>= 1) mu += __shfl_xor(mu, d);
    mu *= (1.0f / 64.0f);
    float dv = o - mu;
    float var = dv * dv;
#pragma unroll
    for (int d = 32; d > 0; d >>= 1) var += __shfl_xor(var, d);
    var *= (1.0f / 64.0f);
    out[(size_t)n * 64 + lane] = dv * rsqrtf(var + LN_EPS) * gamma[lane] + beta[lane];
}

// ---------------------------------------------------------------------------
extern "C" void kernel_launch(void* const* d_in, const int* in_sizes, int n_in,
                              void* d_out, int out_size, void* d_ws, size_t ws_size,
                              hipStream_t stream) {
    const float* X        = (const float*)d_in[0];
    const int*   ei       = (const int*)d_in[1];
    const float* W        = (const float*)d_in[2];
    const float* att_src  = (const float*)d_in[3];
    const float* att_dst  = (const float*)d_in[4];
    const float* bias     = (const float*)d_in[5];
    const float* ln_gamma = (const float*)d_in[6];
    const float* ln_beta  = (const float*)d_in[7];
    float* out = (float*)d_out;

    const int N = in_sizes[0] / 128;
    const int E = in_sizes[1] / 2;

    char* ws = (char*)d_ws;
    size_t off = 0;
    auto alloc = [&](size_t bytes) {
        size_t o = off;
        off += (bytes + 255) & ~(size_t)255;
        return o;
    };
    float* xbuf      = (float*)(ws + alloc((size_t)N * 128 * 4));
    float4* aAtt     = (float4*)(ws + alloc((size_t)N * 4 * 4));
    int* counts      = (int*)(ws + alloc((size_t)N * 4));
    int* row_ptr     = (int*)(ws + alloc((size_t)(N + 1) * 4));
    int* cursor      = (int*)(ws + alloc((size_t)N * 4));
    int* blockSums   = (int*)(ws + alloc(256 * 4));
    int* csr_src     = (int*)(ws + alloc((size_t)E * 4));

    hipMemsetAsync(counts, 0, (size_t)N * 4, stream);

    k_gemm<<<(N + 31) / 32, 256, 0, stream>>>(X, W, xbuf, N);
    k_att<<<(N + 3) / 4, 256, 0, stream>>>(xbuf, att_src, att_dst, aAtt, N);
    k_hist<<<(E + 255) / 256, 256, 0, stream>>>(ei, counts, E);
    const int nb = (N + 1023) / 1024;   // <= 256 for N <= 262144
    k_scan1<<<nb, 256, 0, stream>>>(counts, blockSums, N);
    k_scan2<<<1, 256, 0, stream>>>(blockSums, nb);
    k_scan3<<<nb, 256, 0, stream>>>(counts, blockSums, row_ptr, cursor, N, E);
    k_scatter<<<(E + 255) / 256, 256, 0, stream>>>(ei, cursor, csr_src, E);
    k_agg<<<(N + 3) / 4, 256, 0, stream>>>(xbuf, (const float2*)aAtt, row_ptr,
                                           csr_src, bias, ln_gamma, ln_beta, out, N);
}

// Round 2
// 407.896 us; speedup vs baseline: 1.5043x; 1.5043x over previous
//
#include <hip/hip_runtime.h>
#include <hip/hip_bf16.h>

#define NEG_SLOPE 0.2f
#define LN_EPS 1e-5f
#define SM_EPS 1e-16f

typedef __attribute__((ext_vector_type(8))) short bf16x8;
typedef __attribute__((ext_vector_type(4))) float f32x4;

__device__ inline unsigned short f2bf(float f) {
    unsigned u = __float_as_uint(f);
    return (unsigned short)((u + 0x7FFFu + ((u >> 16) & 1u)) >> 16);
}

// ---------------------------------------------------------------------------
// K1: fused bf16-MFMA GEMM + attention dots + bf16 pack.
//   x = X @ W^T   (X:[N,128] f32 -> bf16, W:[128,128] f32 -> bf16)
// Block: 256 thr = 4 waves, 64 rows/block. Wave w owns rows w*16..+15,
// all 128 output cols via 8 col-tiles of 16 (mfma_f32_16x16x32_bf16).
// LDS: Ws[n][k] bf16 (n=out col, k padded 128->136), Xs[m][k] bf16 (pad 136).
// Pad 136: row stride 68 dwords -> b128 frag reads spread 8 lanes/bank (floor).
// Epilogue: per row, a_src/a_dst dots via 16-lane xor reduction; x written as
// packed dword bf16(head0 f) | bf16(head1 f)<<16 at xp[row*64+f].
// ---------------------------------------------------------------------------
__global__ __launch_bounds__(256) void k_gemm(const float* __restrict__ X,
                                              const float* __restrict__ W,
                                              const float* __restrict__ att_src,
                                              const float* __restrict__ att_dst,
                                              unsigned int* __restrict__ xp,
                                              float2* __restrict__ aS,
                                              float2* __restrict__ aD, int N) {
    __shared__ unsigned short Ws[128 * 136];  // 34816 B
    __shared__ unsigned short Xs[64 * 136];   // 17408 B
    const int t = threadIdx.x;
    const int b0 = blockIdx.x * 64;
    const int lane = t & 63;
    const int w = t >> 6;
    const int c15 = lane & 15;
    const int quad = lane >> 4;

    // stage W (128 rows x 32 float4) -> bf16
#pragma unroll
    for (int i = 0; i < 16; ++i) {
        int f = i * 256 + t;
        int nr = f >> 5;
        int q = f & 31;
        float4 v = reinterpret_cast<const float4*>(W)[nr * 32 + q];
        ushort4 b;
        b.x = f2bf(v.x); b.y = f2bf(v.y); b.z = f2bf(v.z); b.w = f2bf(v.w);
        *reinterpret_cast<ushort4*>(&Ws[nr * 136 + q * 4]) = b;
    }
    // stage X tile (64 rows x 32 float4) -> bf16
#pragma unroll
    for (int i = 0; i < 8; ++i) {
        int f = i * 256 + t;
        int m = f >> 5;
        int q = f & 31;
        int gr = b0 + m;
        if (gr >= N) gr = N - 1;
        float4 v = reinterpret_cast<const float4*>(X)[(size_t)gr * 32 + q];
        ushort4 b;
        b.x = f2bf(v.x); b.y = f2bf(v.y); b.z = f2bf(v.z); b.w = f2bf(v.w);
        *reinterpret_cast<ushort4*>(&Xs[m * 136 + q * 4]) = b;
    }
    __syncthreads();

    f32x4 acc[8];
#pragma unroll
    for (int ct = 0; ct < 8; ++ct) acc[ct] = (f32x4){0.f, 0.f, 0.f, 0.f};

#pragma unroll
    for (int kc = 0; kc < 4; ++kc) {
        bf16x8 af = *reinterpret_cast<const bf16x8*>(
            &Xs[(w * 16 + c15) * 136 + kc * 32 + quad * 8]);
#pragma unroll
        for (int ct = 0; ct < 8; ++ct) {
            bf16x8 bfr = *reinterpret_cast<const bf16x8*>(
                &Ws[(ct * 16 + c15) * 136 + kc * 32 + quad * 8]);
            acc[ct] = __builtin_amdgcn_mfma_f32_16x16x32_bf16(af, bfr, acc[ct], 0, 0, 0);
        }
    }

    // epilogue: attention dots + packed bf16 write
    float attS[8], attD[8];
#pragma unroll
    for (int ct = 0; ct < 8; ++ct) {
        attS[ct] = att_src[ct * 16 + c15];   // flat [H*64] layout == col index
        attD[ct] = att_dst[ct * 16 + c15];
    }

#pragma unroll
    for (int r = 0; r < 4; ++r) {
        int row = b0 + w * 16 + quad * 4 + r;
        float s0 = 0.f, s1 = 0.f, d0 = 0.f, d1 = 0.f;
#pragma unroll
        for (int ct = 0; ct < 4; ++ct) {
            s0 += acc[ct][r] * attS[ct];
            d0 += acc[ct][r] * attD[ct];
            s1 += acc[ct + 4][r] * attS[ct + 4];
            d1 += acc[ct + 4][r] * attD[ct + 4];
        }
#pragma unroll
        for (int o = 1; o < 16; o <<= 1) {
            s0 += __shfl_xor(s0, o);
            s1 += __shfl_xor(s1, o);
            d0 += __shfl_xor(d0, o);
            d1 += __shfl_xor(d1, o);
        }
        if (row < N) {
#pragma unroll
            for (int ct = 0; ct < 4; ++ct) {
                unsigned int p = (unsigned int)f2bf(acc[ct][r]) |
                                 ((unsigned int)f2bf(acc[ct + 4][r]) << 16);
                xp[(size_t)row * 64 + ct * 16 + c15] = p;
            }
            if (c15 == 0) {
                aS[row] = make_float2(s0, s1);
                aD[row] = make_float2(d0, d1);
            }
        }
    }
}

// ---------------------------------------------------------------------------
// CSR build: histogram -> 3-kernel exclusive scan -> scatter
// ---------------------------------------------------------------------------
__global__ void k_hist(const int* __restrict__ ei, int* __restrict__ counts, int E) {
    int i = blockIdx.x * 256 + threadIdx.x;
    if (i < E) atomicAdd(&counts[ei[E + i]], 1);
}

__global__ __launch_bounds__(256) void k_scan1(const int* __restrict__ counts,
                                               int* __restrict__ blockSums, int N) {
    __shared__ int lds[4];
    const int t = threadIdx.x;
    int base = blockIdx.x * 1024 + t * 4;
    int s = 0;
    for (int c = 0; c < 4; ++c) {
        int i = base + c;
        if (i < N) s += counts[i];
    }
    int lane = t & 63, w = t >> 6;
    for (int o = 32; o > 0; o >>= 1) s += __shfl_down(s, o);
    if (lane == 0) lds[w] = s;
    __syncthreads();
    if (t == 0) blockSums[blockIdx.x] = lds[0] + lds[1] + lds[2] + lds[3];
}

__global__ void k_scan2(int* __restrict__ blockSums, int nb) {
    __shared__ int buf[256];
    const int t = threadIdx.x;
    int v = (t < nb) ? blockSums[t] : 0;
    buf[t] = v;
    __syncthreads();
    for (int o = 1; o < 256; o <<= 1) {
        int u = (t >= o) ? buf[t - o] : 0;
        __syncthreads();
        buf[t] += u;
        __syncthreads();
    }
    if (t < nb) blockSums[t] = buf[t] - v;   // exclusive
}

__global__ __launch_bounds__(256) void k_scan3(const int* __restrict__ counts,
                                               const int* __restrict__ blockSums,
                                               int* __restrict__ row_ptr,
                                               int* __restrict__ cursor, int N, int E) {
    __shared__ int lds[4];
    const int t = threadIdx.x;
    int base = blockIdx.x * 1024 + t * 4;
    int c[4];
    int s = 0;
#pragma unroll
    for (int i = 0; i < 4; ++i) {
        int idx = base + i;
        c[i] = (idx < N) ? counts[idx] : 0;
        s += c[i];
    }
    int lane = t & 63, w = t >> 6;
    int incl = s;
#pragma unroll
    for (int o = 1; o < 64; o <<= 1) {
        int u = __shfl_up(incl, o);
        if (lane >= o) incl += u;
    }
    if (lane == 63) lds[w] = incl;
    __syncthreads();
    if (t == 0) {
        int run = 0;
        for (int i = 0; i < 4; ++i) { int tmp = lds[i]; lds[i] = run; run += tmp; }
    }
    __syncthreads();
    int off = blockSums[blockIdx.x] + lds[w] + incl - s;
#pragma unroll
    for (int i = 0; i < 4; ++i) {
        int idx = base + i;
        if (idx < N) {
            row_ptr[idx] = off;
            cursor[idx] = off;
            off += c[i];
        }
    }
    if (blockIdx.x == 0 && t == 0) row_ptr[N] = E;
}

__global__ void k_scatter(const int* __restrict__ ei, int* __restrict__ cursor,
                          int* __restrict__ csr_src, int E) {
    int i = blockIdx.x * 256 + threadIdx.x;
    if (i < E) {
        int s = ei[i];
        int d = ei[E + i];
        int pos = atomicAdd(&cursor[d], 1);
        csr_src[pos] = s;
    }
}

// ---------------------------------------------------------------------------
// K5: per-dst aggregation + head-mean + bias + LayerNorm.
// One wave per node, lane = feature. xp rows are packed bf16 (h0|h1) so each
// edge gathers 256B (one dword/lane). Unrolled by 2 for memory-level par.
// ---------------------------------------------------------------------------
__device__ inline float bf_lo(unsigned int v) { return __uint_as_float(v << 16); }
__device__ inline float bf_hi(unsigned int v) { return __uint_as_float(v & 0xffff0000u); }

__global__ __launch_bounds__(256) void k_agg(const unsigned int* __restrict__ xp,
                                             const float2* __restrict__ aS,
                                             const float2* __restrict__ aD,
                                             const int* __restrict__ row_ptr,
                                             const int* __restrict__ csr_src,
                                             const float* __restrict__ bias,
                                             const float* __restrict__ gamma,
                                             const float* __restrict__ beta,
                                             float* __restrict__ out, int N) {
    const int w = threadIdx.x >> 6, lane = threadIdx.x & 63;
    const int n = blockIdx.x * 4 + w;
    if (n >= N) return;

    float2 as = aS[n];
    float2 ad = aD[n];

    // self loop
    float e0 = as.x + ad.x; e0 = fmaxf(e0, NEG_SLOPE * e0);
    float e1 = as.y + ad.y; e1 = fmaxf(e1, NEG_SLOPE * e1);
    float w0 = __expf(e0), w1 = __expf(e1);
    unsigned int vs = xp[(size_t)n * 64 + lane];
    float D0 = w0, D1 = w1;
    float S0 = w0 * bf_lo(vs);
    float S1 = w1 * bf_hi(vs);

    const int jb = row_ptr[n], je = row_ptr[n + 1];
    int j = jb;
    for (; j + 1 < je; j += 2) {
        int sA = csr_src[j];
        int sB = csr_src[j + 1];
        float2 aA = aS[sA];
        float2 aB = aS[sB];
        unsigned int vA = xp[(size_t)sA * 64 + lane];
        unsigned int vB = xp[(size_t)sB * 64 + lane];
        float fA0 = aA.x + ad.x; fA0 = fmaxf(fA0, NEG_SLOPE * fA0);
        float fA1 = aA.y + ad.y; fA1 = fmaxf(fA1, NEG_SLOPE * fA1);
        float fB0 = aB.x + ad.x; fB0 = fmaxf(fB0, NEG_SLOPE * fB0);
        float fB1 = aB.y + ad.y; fB1 = fmaxf(fB1, NEG_SLOPE * fB1);
        float uA0 = __expf(fA0), uA1 = __expf(fA1);
        float uB0 = __expf(fB0), uB1 = __expf(fB1);
        D0 += uA0 + uB0;
        D1 += uA1 + uB1;
        S0 += uA0 * bf_lo(vA) + uB0 * bf_lo(vB);
        S1 += uA1 * bf_hi(vA) + uB1 * bf_hi(vB);
    }
    if (j < je) {
        int sA = csr_src[j];
        float2 aA = aS[sA];
        unsigned int vA = xp[(size_t)sA * 64 + lane];
        float fA0 = aA.x + ad.x; fA0 = fmaxf(fA0, NEG_SLOPE * fA0);
        float fA1 = aA.y + ad.y; fA1 = fmaxf(fA1, NEG_SLOPE * fA1);
        float uA0 = __expf(fA0), uA1 = __expf(fA1);
        D0 += uA0; D1 += uA1;
        S0 += uA0 * bf_lo(vA);
        S1 += uA1 * bf_hi(vA);
    }

    float o = 0.5f * (S0 / (D0 + SM_EPS) + S1 / (D1 + SM_EPS)) + bias[lane];

    float mu = o;
#pragma unroll
    for (int d = 32; d > 0; d >>= 1) mu += __shfl_xor(mu, d);
    mu *= (1.0f / 64.0f);
    float dv = o - mu;
    float var = dv * dv;
#pragma unroll
    for (int d = 32; d > 0; d >>= 1) var += __shfl_xor(var, d);
    var *= (1.0f / 64.0f);
    out[(size_t)n * 64 + lane] = dv * rsqrtf(var + LN_EPS) * gamma[lane] + beta[lane];
}

// ---------------------------------------------------------------------------
extern "C" void kernel_launch(void* const* d_in, const int* in_sizes, int n_in,
                              void* d_out, int out_size, void* d_ws, size_t ws_size,
                              hipStream_t stream) {
    const float* X        = (const float*)d_in[0];
    const int*   ei       = (const int*)d_in[1];
    const float* W        = (const float*)d_in[2];
    const float* att_src  = (const float*)d_in[3];
    const float* att_dst  = (const float*)d_in[4];
    const float* bias     = (const float*)d_in[5];
    const float* ln_gamma = (const float*)d_in[6];
    const float* ln_beta  = (const float*)d_in[7];
    float* out = (float*)d_out;

    const int N = in_sizes[0] / 128;
    const int E = in_sizes[1] / 2;

    char* ws = (char*)d_ws;
    size_t off = 0;
    auto alloc = [&](size_t bytes) {
        size_t o = off;
        off += (bytes + 255) & ~(size_t)255;
        return o;
    };
    unsigned int* xp = (unsigned int*)(ws + alloc((size_t)N * 64 * 4));
    float2* aS       = (float2*)(ws + alloc((size_t)N * 8));
    float2* aD       = (float2*)(ws + alloc((size_t)N * 8));
    int* counts      = (int*)(ws + alloc((size_t)N * 4));
    int* row_ptr     = (int*)(ws + alloc((size_t)(N + 1) * 4));
    int* cursor      = (int*)(ws + alloc((size_t)N * 4));
    int* blockSums   = (int*)(ws + alloc(256 * 4));
    int* csr_src     = (int*)(ws + alloc((size_t)E * 4));

    hipMemsetAsync(counts, 0, (size_t)N * 4, stream);

    k_gemm<<<(N + 63) / 64, 256, 0, stream>>>(X, W, att_src, att_dst, xp, aS, aD, N);
    k_hist<<<(E + 255) / 256, 256, 0, stream>>>(ei, counts, E);
    const int nb = (N + 1023) / 1024;
    k_scan1<<<nb, 256, 0, stream>>>(counts, blockSums, N);
    k_scan2<<<1, 256, 0, stream>>>(blockSums, nb);
    k_scan3<<<nb, 256, 0, stream>>>(counts, blockSums, row_ptr, cursor, N, E);
    k_scatter<<<(E + 255) / 256, 256, 0, stream>>>(ei, cursor, csr_src, E);
    k_agg<<<(N + 3) / 4, 256, 0, stream>>>(xp, aS, aD, row_ptr, csr_src,
                                           bias, ln_gamma, ln_beta, out, N);
}

// Round 3
// 271.453 us; speedup vs baseline: 2.2604x; 1.5026x over previous
//
#include <hip/hip_runtime.h>
#include <hip/hip_bf16.h>

#define NEG_SLOPE 0.2f
#define LN_EPS 1e-5f
#define SM_EPS 1e-16f

typedef __attribute__((ext_vector_type(8))) short bf16x8;
typedef __attribute__((ext_vector_type(4))) float f32x4;

__device__ inline unsigned short f2bf(float f) {
    unsigned u = __float_as_uint(f);
    return (unsigned short)((u + 0x7FFFu + ((u >> 16) & 1u)) >> 16);
}

// ---------------------------------------------------------------------------
// K1: fused bf16-MFMA GEMM + attention dots + bf16 pack. (unchanged, verified)
// ---------------------------------------------------------------------------
__global__ __launch_bounds__(256) void k_gemm(const float* __restrict__ X,
                                              const float* __restrict__ W,
                                              const float* __restrict__ att_src,
                                              const float* __restrict__ att_dst,
                                              unsigned int* __restrict__ xp,
                                              float2* __restrict__ aS,
                                              float2* __restrict__ aD, int N) {
    __shared__ unsigned short Ws[128 * 136];
    __shared__ unsigned short Xs[64 * 136];
    const int t = threadIdx.x;
    const int b0 = blockIdx.x * 64;
    const int lane = t & 63;
    const int w = t >> 6;
    const int c15 = lane & 15;
    const int quad = lane >> 4;

#pragma unroll
    for (int i = 0; i < 16; ++i) {
        int f = i * 256 + t;
        int nr = f >> 5;
        int q = f & 31;
        float4 v = reinterpret_cast<const float4*>(W)[nr * 32 + q];
        ushort4 b;
        b.x = f2bf(v.x); b.y = f2bf(v.y); b.z = f2bf(v.z); b.w = f2bf(v.w);
        *reinterpret_cast<ushort4*>(&Ws[nr * 136 + q * 4]) = b;
    }
#pragma unroll
    for (int i = 0; i < 8; ++i) {
        int f = i * 256 + t;
        int m = f >> 5;
        int q = f & 31;
        int gr = b0 + m;
        if (gr >= N) gr = N - 1;
        float4 v = reinterpret_cast<const float4*>(X)[(size_t)gr * 32 + q];
        ushort4 b;
        b.x = f2bf(v.x); b.y = f2bf(v.y); b.z = f2bf(v.z); b.w = f2bf(v.w);
        *reinterpret_cast<ushort4*>(&Xs[m * 136 + q * 4]) = b;
    }
    __syncthreads();

    f32x4 acc[8];
#pragma unroll
    for (int ct = 0; ct < 8; ++ct) acc[ct] = (f32x4){0.f, 0.f, 0.f, 0.f};

#pragma unroll
    for (int kc = 0; kc < 4; ++kc) {
        bf16x8 af = *reinterpret_cast<const bf16x8*>(
            &Xs[(w * 16 + c15) * 136 + kc * 32 + quad * 8]);
#pragma unroll
        for (int ct = 0; ct < 8; ++ct) {
            bf16x8 bfr = *reinterpret_cast<const bf16x8*>(
                &Ws[(ct * 16 + c15) * 136 + kc * 32 + quad * 8]);
            acc[ct] = __builtin_amdgcn_mfma_f32_16x16x32_bf16(af, bfr, acc[ct], 0, 0, 0);
        }
    }

    float attS[8], attD[8];
#pragma unroll
    for (int ct = 0; ct < 8; ++ct) {
        attS[ct] = att_src[ct * 16 + c15];
        attD[ct] = att_dst[ct * 16 + c15];
    }

#pragma unroll
    for (int r = 0; r < 4; ++r) {
        int row = b0 + w * 16 + quad * 4 + r;
        float s0 = 0.f, s1 = 0.f, d0 = 0.f, d1 = 0.f;
#pragma unroll
        for (int ct = 0; ct < 4; ++ct) {
            s0 += acc[ct][r] * attS[ct];
            d0 += acc[ct][r] * attD[ct];
            s1 += acc[ct + 4][r] * attS[ct + 4];
            d1 += acc[ct + 4][r] * attD[ct + 4];
        }
#pragma unroll
        for (int o = 1; o < 16; o <<= 1) {
            s0 += __shfl_xor(s0, o);
            s1 += __shfl_xor(s1, o);
            d0 += __shfl_xor(d0, o);
            d1 += __shfl_xor(d1, o);
        }
        if (row < N) {
#pragma unroll
            for (int ct = 0; ct < 4; ++ct) {
                unsigned int p = (unsigned int)f2bf(acc[ct][r]) |
                                 ((unsigned int)f2bf(acc[ct + 4][r]) << 16);
                xp[(size_t)row * 64 + ct * 16 + c15] = p;
            }
            if (c15 == 0) {
                aS[row] = make_float2(s0, s1);
                aD[row] = make_float2(d0, d1);
            }
        }
    }
}

// ---------------------------------------------------------------------------
// Atomic-free CSR build via 2-level counting sort on dst.
// Level 1: 512 buckets = dst>>8. Level 2: per-bucket LDS count over 256 dst.
// ---------------------------------------------------------------------------
#define SORT_CHUNK 4096
#define NBIN 512

// kA: per-block LDS histogram of dst>>8 -> blockCnt[bin*NB + blk]
__global__ __launch_bounds__(256) void k_sort_count(const int* __restrict__ ei,
                                                    int* __restrict__ blockCnt,
                                                    int E, int NB) {
    __shared__ int hist[NBIN];
    const int t = threadIdx.x;
    for (int i = t; i < NBIN; i += 256) hist[i] = 0;
    __syncthreads();
    const int base = blockIdx.x * SORT_CHUNK;
#pragma unroll
    for (int k = 0; k < 16; ++k) {
        int i = base + k * 256 + t;
        if (i < E) atomicAdd(&hist[ei[E + i] >> 8], 1);
    }
    __syncthreads();
    for (int i = t; i < NBIN; i += 256)
        blockCnt[i * NB + blockIdx.x] = hist[i];
}

// scan stage 1: per-1024-chunk sums
__global__ __launch_bounds__(256) void k_scan1(const int* __restrict__ data,
                                               int* __restrict__ blockSums, int M) {
    __shared__ int lds[4];
    const int t = threadIdx.x;
    int base = blockIdx.x * 1024 + t * 4;
    int s = 0;
    for (int c = 0; c < 4; ++c) {
        int i = base + c;
        if (i < M) s += data[i];
    }
    int lane = t & 63, w = t >> 6;
    for (int o = 32; o > 0; o >>= 1) s += __shfl_down(s, o);
    if (lane == 0) lds[w] = s;
    __syncthreads();
    if (t == 0) blockSums[blockIdx.x] = lds[0] + lds[1] + lds[2] + lds[3];
}

// scan stage 2: exclusive scan of up to 256 block sums
__global__ void k_scan2(int* __restrict__ blockSums, int nb) {
    __shared__ int buf[256];
    const int t = threadIdx.x;
    int v = (t < nb) ? blockSums[t] : 0;
    buf[t] = v;
    __syncthreads();
    for (int o = 1; o < 256; o <<= 1) {
        int u = (t >= o) ? buf[t - o] : 0;
        __syncthreads();
        buf[t] += u;
        __syncthreads();
    }
    if (t < nb) blockSums[t] = buf[t] - v;
}

// scan stage 3: in-place exclusive prefix
__global__ __launch_bounds__(256) void k_scan3(int* __restrict__ data,
                                               const int* __restrict__ blockSums, int M) {
    __shared__ int lds[4];
    const int t = threadIdx.x;
    int base = blockIdx.x * 1024 + t * 4;
    int c[4];
    int s = 0;
#pragma unroll
    for (int i = 0; i < 4; ++i) {
        int idx = base + i;
        c[i] = (idx < M) ? data[idx] : 0;
        s += c[i];
    }
    int lane = t & 63, w = t >> 6;
    int incl = s;
#pragma unroll
    for (int o = 1; o < 64; o <<= 1) {
        int u = __shfl_up(incl, o);
        if (lane >= o) incl += u;
    }
    if (lane == 63) lds[w] = incl;
    __syncthreads();
    if (t == 0) {
        int run = 0;
        for (int i = 0; i < 4; ++i) { int tmp = lds[i]; lds[i] = run; run += tmp; }
    }
    __syncthreads();
    int off = blockSums[blockIdx.x] + lds[w] + incl - s;
#pragma unroll
    for (int i = 0; i < 4; ++i) {
        int idx = base + i;
        if (idx < M) { data[idx] = off; off += c[i]; }
    }
}

// kC: scatter (dst,src) pairs into bucket-contiguous tmp (LDS cursors, no
// global atomics; per-(bin,block) writes are contiguous runs).
__global__ __launch_bounds__(256) void k_sort_scatter(const int* __restrict__ ei,
                                                      const int* __restrict__ scanned,
                                                      uint2* __restrict__ tmp,
                                                      int E, int NB) {
    __shared__ int off[NBIN];
    const int t = threadIdx.x;
    for (int i = t; i < NBIN; i += 256) off[i] = scanned[i * NB + blockIdx.x];
    __syncthreads();
    const int base = blockIdx.x * SORT_CHUNK;
#pragma unroll
    for (int k = 0; k < 16; ++k) {
        int i = base + k * 256 + t;
        if (i < E) {
            int s = ei[i];
            int d = ei[E + i];
            int p = atomicAdd(&off[d >> 8], 1);
            tmp[p] = make_uint2((unsigned)d, (unsigned)s);
        }
    }
}

// kD: one block per bucket (256 dst values). LDS count + block scan ->
// row_ptr and fully-coalesced csr_src. Reads tmp twice (L2/L3-warm).
__global__ __launch_bounds__(256) void k_bucket(const uint2* __restrict__ tmp,
                                                const int* __restrict__ scanned,
                                                int* __restrict__ csr_src,
                                                int* __restrict__ row_ptr,
                                                int E, int NB, int N) {
    __shared__ int cnt[256];
    __shared__ int cur[256];
    __shared__ int lds[4];
    const int t = threadIdx.x;
    const int b = blockIdx.x;
    const int start = scanned[b * NB];
    const int end = (b + 1 < NBIN) ? scanned[(b + 1) * NB] : E;
    const int m = end - start;

    cnt[t] = 0;
    __syncthreads();
    for (int k = t; k < m; k += 256) {
        uint2 e = tmp[start + k];
        atomicAdd(&cnt[e.x & 255], 1);
    }
    __syncthreads();

    // block exclusive scan of cnt[256]
    int v = cnt[t];
    int lane = t & 63, w = t >> 6;
    int incl = v;
#pragma unroll
    for (int o = 1; o < 64; o <<= 1) {
        int u = __shfl_up(incl, o);
        if (lane >= o) incl += u;
    }
    if (lane == 63) lds[w] = incl;
    __syncthreads();
    if (t == 0) {
        int run = 0;
        for (int i = 0; i < 4; ++i) { int tmpv = lds[i]; lds[i] = run; run += tmpv; }
    }
    __syncthreads();
    int excl = lds[w] + incl - v;
    cur[t] = start + excl;
    int idx = b * 256 + t;
    if (idx < N) row_ptr[idx] = start + excl;
    if (b == 0 && t == 0) row_ptr[N] = E;
    __syncthreads();

    for (int k = t; k < m; k += 256) {
        uint2 e = tmp[start + k];
        int p = atomicAdd(&cur[e.x & 255], 1);
        csr_src[p] = (int)e.y;
    }
}

// ---------------------------------------------------------------------------
// K5: per-dst aggregation + head-mean + bias + LayerNorm. Unroll-4 gathers.
// ---------------------------------------------------------------------------
__device__ inline float bf_lo(unsigned int v) { return __uint_as_float(v << 16); }
__device__ inline float bf_hi(unsigned int v) { return __uint_as_float(v & 0xffff0000u); }

__global__ __launch_bounds__(256) void k_agg(const unsigned int* __restrict__ xp,
                                             const float2* __restrict__ aS,
                                             const float2* __restrict__ aD,
                                             const int* __restrict__ row_ptr,
                                             const int* __restrict__ csr_src,
                                             const float* __restrict__ bias,
                                             const float* __restrict__ gamma,
                                             const float* __restrict__ beta,
                                             float* __restrict__ out, int N) {
    const int w = threadIdx.x >> 6, lane = threadIdx.x & 63;
    const int n = blockIdx.x * 4 + w;
    if (n >= N) return;

    float2 as = aS[n];
    float2 ad = aD[n];

    float e0 = as.x + ad.x; e0 = fmaxf(e0, NEG_SLOPE * e0);
    float e1 = as.y + ad.y; e1 = fmaxf(e1, NEG_SLOPE * e1);
    float w0 = __expf(e0), w1 = __expf(e1);
    unsigned int vself = xp[(size_t)n * 64 + lane];
    float D0 = w0, D1 = w1;
    float S0 = w0 * bf_lo(vself);
    float S1 = w1 * bf_hi(vself);

    const int jb = row_ptr[n], je = row_ptr[n + 1];
    int j = jb;
    for (; j + 3 < je; j += 4) {
        int s0 = csr_src[j], s1 = csr_src[j + 1];
        int s2 = csr_src[j + 2], s3 = csr_src[j + 3];
        float2 a0 = aS[s0], a1 = aS[s1], a2 = aS[s2], a3 = aS[s3];
        unsigned int v0 = xp[(size_t)s0 * 64 + lane];
        unsigned int v1 = xp[(size_t)s1 * 64 + lane];
        unsigned int v2 = xp[(size_t)s2 * 64 + lane];
        unsigned int v3 = xp[(size_t)s3 * 64 + lane];
        float f00 = a0.x + ad.x; f00 = fmaxf(f00, NEG_SLOPE * f00);
        float f01 = a0.y + ad.y; f01 = fmaxf(f01, NEG_SLOPE * f01);
        float f10 = a1.x + ad.x; f10 = fmaxf(f10, NEG_SLOPE * f10);
        float f11 = a1.y + ad.y; f11 = fmaxf(f11, NEG_SLOPE * f11);
        float f20 = a2.x + ad.x; f20 = fmaxf(f20, NEG_SLOPE * f20);
        float f21 = a2.y + ad.y; f21 = fmaxf(f21, NEG_SLOPE * f21);
        float f30 = a3.x + ad.x; f30 = fmaxf(f30, NEG_SLOPE * f30);
        float f31 = a3.y + ad.y; f31 = fmaxf(f31, NEG_SLOPE * f31);
        float u00 = __expf(f00), u01 = __expf(f01);
        float u10 = __expf(f10), u11 = __expf(f11);
        float u20 = __expf(f20), u21 = __expf(f21);
        float u30 = __expf(f30), u31 = __expf(f31);
        D0 += u00 + u10 + u20 + u30;
        D1 += u01 + u11 + u21 + u31;
        S0 += u00 * bf_lo(v0) + u10 * bf_lo(v1) + u20 * bf_lo(v2) + u30 * bf_lo(v3);
        S1 += u01 * bf_hi(v0) + u11 * bf_hi(v1) + u21 * bf_hi(v2) + u31 * bf_hi(v3);
    }
    for (; j < je; ++j) {
        int sA = csr_src[j];
        float2 aA = aS[sA];
        unsigned int vA = xp[(size_t)sA * 64 + lane];
        float fA0 = aA.x + ad.x; fA0 = fmaxf(fA0, NEG_SLOPE * fA0);
        float fA1 = aA.y + ad.y; fA1 = fmaxf(fA1, NEG_SLOPE * fA1);
        float uA0 = __expf(fA0), uA1 = __expf(fA1);
        D0 += uA0; D1 += uA1;
        S0 += uA0 * bf_lo(vA);
        S1 += uA1 * bf_hi(vA);
    }

    float o = 0.5f * (S0 / (D0 + SM_EPS) + S1 / (D1 + SM_EPS)) + bias[lane];

    float mu = o;
#pragma unroll
    for (int d = 32; d > 0; d >>= 1) mu += __shfl_xor(mu, d);
    mu *= (1.0f / 64.0f);
    float dv = o - mu;
    float var = dv * dv;
#pragma unroll
    for (int d = 32; d > 0; d >>= 1) var += __shfl_xor(var, d);
    var *= (1.0f / 64.0f);
    out[(size_t)n * 64 + lane] = dv * rsqrtf(var + LN_EPS) * gamma[lane] + beta[lane];
}

// ---------------------------------------------------------------------------
extern "C" void kernel_launch(void* const* d_in, const int* in_sizes, int n_in,
                              void* d_out, int out_size, void* d_ws, size_t ws_size,
                              hipStream_t stream) {
    const float* X        = (const float*)d_in[0];
    const int*   ei       = (const int*)d_in[1];
    const float* W        = (const float*)d_in[2];
    const float* att_src  = (const float*)d_in[3];
    const float* att_dst  = (const float*)d_in[4];
    const float* bias     = (const float*)d_in[5];
    const float* ln_gamma = (const float*)d_in[6];
    const float* ln_beta  = (const float*)d_in[7];
    float* out = (float*)d_out;

    const int N = in_sizes[0] / 128;
    const int E = in_sizes[1] / 2;
    const int NB = (E + SORT_CHUNK - 1) / SORT_CHUNK;       // blocks in sort pass
    const int NBUCK = (N + 255) / 256;                      // level-2 buckets
    const int M = NBIN * NB;                                // count-array length

    char* ws = (char*)d_ws;
    size_t off = 0;
    auto alloc = [&](size_t bytes) {
        size_t o = off;
        off += (bytes + 255) & ~(size_t)255;
        return o;
    };
    unsigned int* xp = (unsigned int*)(ws + alloc((size_t)N * 64 * 4));
    float2* aS       = (float2*)(ws + alloc((size_t)N * 8));
    float2* aD       = (float2*)(ws + alloc((size_t)N * 8));
    int* row_ptr     = (int*)(ws + alloc((size_t)(N + 1) * 4));
    int* csr_src     = (int*)(ws + alloc((size_t)E * 4));
    uint2* tmp       = (uint2*)(ws + alloc((size_t)E * 8));
    int* blockCnt    = (int*)(ws + alloc((size_t)M * 4));
    int* blockSums   = (int*)(ws + alloc(256 * 4));

    k_gemm<<<(N + 63) / 64, 256, 0, stream>>>(X, W, att_src, att_dst, xp, aS, aD, N);

    k_sort_count<<<NB, 256, 0, stream>>>(ei, blockCnt, E, NB);
    const int nb = (M + 1023) / 1024;                       // 196 <= 256
    k_scan1<<<nb, 256, 0, stream>>>(blockCnt, blockSums, M);
    k_scan2<<<1, 256, 0, stream>>>(blockSums, nb);
    k_scan3<<<nb, 256, 0, stream>>>(blockCnt, blockSums, M);
    k_sort_scatter<<<NB, 256, 0, stream>>>(ei, blockCnt, tmp, E, NB);
    k_bucket<<<NBUCK, 256, 0, stream>>>(tmp, blockCnt, csr_src, row_ptr, E, NB, N);

    k_agg<<<(N + 3) / 4, 256, 0, stream>>>(xp, aS, aD, row_ptr, csr_src,
                                           bias, ln_gamma, ln_beta, out, N);
}